// Round 22
// baseline (2118.153 us; speedup 1.0000x reference)
//
#include <hip/hip_runtime.h>
#include <math.h>

// Chamfer distance, B=8, N=8192, fp32 in, fp32 scalar out.
//
// R22 — EXACT GRID NN (algorithmic): brute force = 1.07e9 pairs; a 32^3
// spatial grid with expanding-ring search needs ~1e7.  Counting-sort each
// (cloud,batch) into cells, then one lane per query walks Chebyshev rings
// outward with the exact stop bound best <= margin^2 (margin = distance
// from q to the scanned-box boundary; safe for clamped outliers since
// clamping projects onto a convex box containing interior queries).
// Min over a set is EXACT in f32 -> deterministic regardless of scatter
// order; merged via u64 fixed-point atomicAdd.  Queries are consumed in
// sorted order so a wave's 64 lanes share cells -> L1-served gathers.
//
// Fallback: if ws_size < ~6.3MB, run the proven R15 MFMA kernel instead.

#define NPTS   8192
#define NB     8
#define NPC    (NB * NPTS)         // 65536
#define TOTALQ (2 * NPC)           // 131072
#define EPSV   1e-12f
#define FXSCALE 67108864.0         // 2^26

// ---- grid params ----
#define G      32
#define CELLS  (G * G * G)         // 32768
#define NG     16                  // (side,b) grids
#define XMIN   (-4.2f)
#define RANGE  (8.4f)
#define INVH   ((float)G / RANGE)
#define H      (RANGE / (float)G)

__device__ __forceinline__ int cellof(float v) {
    int c = (int)floorf((v - XMIN) * INVH);
    return c < 0 ? 0 : (c > G - 1 ? G - 1 : c);
}

// K1: count points per cell (A pre-zeroed by memset); zero the counter.
__global__ __launch_bounds__(256) void ggrid_count(
    const float* __restrict__ xyz1, const float* __restrict__ xyz2,
    unsigned* __restrict__ A, unsigned long long* __restrict__ counter)
{
    const int gid = blockIdx.x * 256 + threadIdx.x;      // [0, TOTALQ)
    if (gid == 0) counter[0] = 0ULL;
    const int side  = gid >> 16;
    const int local = gid & (NPC - 1);
    const float* p = (side ? xyz2 : xyz1) + 3 * (size_t)local;
    const int ci = (cellof(p[2]) << 10) | (cellof(p[1]) << 5) | cellof(p[0]);
    const int g  = (side << 3) | (local >> 13);
    atomicAdd(&A[(g << 15) | ci], 1u);
}

// K2: per-grid exclusive scan (16 blocks x 1024 thr, 32 cells/thread).
// Writes offsets to B and initializes A as the scatter cursor.
__global__ __launch_bounds__(1024) void ggrid_scan(
    unsigned* __restrict__ A, unsigned* __restrict__ B)
{
    const int g = blockIdx.x;                  // [0, NG)
    const int t = threadIdx.x;
    const unsigned gbase = (unsigned)g << 15;

    unsigned mysum = 0;
#pragma unroll
    for (int c = 0; c < 32; ++c) mysum += A[gbase + t * 32 + c];

    __shared__ unsigned ls[1024];
    ls[t] = mysum;
    __syncthreads();
    for (int s = 1; s < 1024; s <<= 1) {
        unsigned v = (t >= s) ? ls[t - s] : 0u;
        __syncthreads();
        ls[t] += v;
        __syncthreads();
    }
    unsigned run = (unsigned)g * NPTS + (ls[t] - mysum);
#pragma unroll
    for (int c = 0; c < 32; ++c) {
        const unsigned idx = gbase + t * 32 + c;
        const unsigned cnt = A[idx];
        B[idx] = run;
        A[idx] = run;          // cursor for scatter
        run += cnt;
    }
}

// K3: scatter points into sorted order C[pos] = (x,y,z,0).
__global__ __launch_bounds__(256) void ggrid_scatter(
    const float* __restrict__ xyz1, const float* __restrict__ xyz2,
    unsigned* __restrict__ A, float4* __restrict__ C)
{
    const int gid = blockIdx.x * 256 + threadIdx.x;
    const int side  = gid >> 16;
    const int local = gid & (NPC - 1);
    const float* p = (side ? xyz2 : xyz1) + 3 * (size_t)local;
    const float x = p[0], y = p[1], z = p[2];
    const int ci = (cellof(z) << 10) | (cellof(y) << 5) | cellof(x);
    const int g  = (side << 3) | (local >> 13);
    const unsigned pos = atomicAdd(&A[(g << 15) | ci], 1u);
    C[pos] = make_float4(x, y, z, 0.0f);
}

// K4: one lane per query (sorted order), expanding-ring exact NN, then
// sqrt + block sum + one u64 fixed-point atomicAdd.
__global__ __launch_bounds__(256) void ggrid_query(
    const float4* __restrict__ C, const unsigned* __restrict__ B,
    unsigned long long* __restrict__ counter)
{
    const int gi   = blockIdx.x * 256 + threadIdx.x;     // [0, TOTALQ)
    const int tid  = threadIdx.x;
    const int lane = tid & 63;
    const int w    = tid >> 6;

    const int g_q  = gi >> 13;                 // [0,16): side*8+b
    const int side = g_q >> 3;
    const int b    = g_q & 7;
    const int g_t  = ((1 - side) << 3) | b;
    const unsigned ct   = (unsigned)g_t << 15; // target cell base in B
    const unsigned tend = (unsigned)(g_t + 1) * NPTS;

    const float4 q = C[gi];
    const int cx = cellof(q.x), cy = cellof(q.y), cz = cellof(q.z);

    float best = 3.4e38f;
    for (int r = 0; r < G; ++r) {
        const int z0 = max(cz - r, 0), z1 = min(cz + r, G - 1);
        const int y0 = max(cy - r, 0), y1 = min(cy + r, G - 1);
        const int x0 = max(cx - r, 0), x1 = min(cx + r, G - 1);
        for (int zz = z0; zz <= z1; ++zz) {
            const int az = abs(zz - cz);
            for (int yy = y0; yy <= y1; ++yy) {
                const int ay = abs(yy - cy);
                for (int xx = x0; xx <= x1; ++xx) {
                    const int md = max(max(abs(xx - cx), ay), az);
                    if (md != r) continue;     // shell only
                    const unsigned ci = (unsigned)((zz << 10) | (yy << 5) | xx);
                    const unsigned s = B[ct | ci];
                    const unsigned e = (ci == CELLS - 1) ? tend : B[ct + ci + 1];
                    for (unsigned j = s; j < e; ++j) {
                        const float4 p = C[j];
                        const float dx = q.x - p.x;
                        const float dy = q.y - p.y;
                        const float dz = q.z - p.z;
                        const float d = fmaf(dx, dx, fmaf(dy, dy, dz * dz));
                        best = fminf(best, d);
                    }
                }
            }
        }
        // Exact stop bound: distance from q to the scanned-box boundary.
        const float lox = XMIN + (cx - r) * H,  hix = XMIN + (cx + r + 1) * H;
        const float loy = XMIN + (cy - r) * H,  hiy = XMIN + (cy + r + 1) * H;
        const float loz = XMIN + (cz - r) * H,  hiz = XMIN + (cz + r + 1) * H;
        float m = fminf(q.x - lox, hix - q.x);
        m = fminf(m, fminf(q.y - loy, hiy - q.y));
        m = fminf(m, fminf(q.z - loz, hiz - q.z));
        if (m > 0.0f && best <= m * m) break;
    }

    float acc = sqrtf(fmaxf(fmaxf(best, 0.0f), EPSV));
#pragma unroll
    for (int off = 1; off < 64; off <<= 1) acc += __shfl_xor(acc, off);

    __shared__ float red[4];
    __syncthreads();
    if (lane == 0) red[w] = acc;
    __syncthreads();
    if (tid == 0) {
        const float s = red[0] + red[1] + red[2] + red[3];
        atomicAdd(counter, (unsigned long long)((double)s * FXSCALE + 0.5));
    }
}

__global__ void chamfer_finalize(
    const unsigned long long* __restrict__ counter, float* __restrict__ out)
{
    out[0] = (float)((double)counter[0] * (1.0 / FXSCALE) / (double)TOTALQ);
}

// ================= R15 fallback (proven 45.5 us) =================
#define BLOCK  256
#define CHUNK  1024
#define COLS   NPTS

typedef _Float16 v8h  __attribute__((ext_vector_type(8)));
typedef float    v16f __attribute__((ext_vector_type(16)));

__global__ __launch_bounds__(256) void chamfer_prep(
    const float* __restrict__ xyz1, const float* __restrict__ xyz2,
    v8h* __restrict__ form, unsigned long long* __restrict__ counter)
{
    const int gid = blockIdx.x * 256 + threadIdx.x;
    if (gid == 0) counter[0] = 0ULL;
    const float* __restrict__ src = (gid < NPC) ? xyz1 : xyz2;
    const int i = (gid < NPC) ? gid : gid - NPC;
    float x = src[3 * i], y = src[3 * i + 1], z = src[3 * i + 2];
    _Float16 xh = (_Float16)x, yh = (_Float16)y, zh = (_Float16)z;
    float xf = (float)xh, yf = (float)yh, zf = (float)zh;
    float n = fmaf(xf, xf, fmaf(yf, yf, zf * zf));
    v8h bv = {};
    bv[0] = xh; bv[1] = yh; bv[2] = zh;
    bv[3] = (_Float16)n; bv[4] = (_Float16)1.0f;
    form[gid] = bv;
}

#define MFMA(va, vb) __builtin_amdgcn_mfma_f32_32x32x16_f16((va), (vb), vzero, 0, 0, 0)

__device__ __forceinline__ unsigned umin2(unsigned a, unsigned b) {
    return a < b ? a : b;
}

__global__ __launch_bounds__(BLOCK, 4) void chamfer_mfma_min(
    const v8h* __restrict__ form, unsigned long long* __restrict__ counter)
{
    const int bid = blockIdx.x;
    const int rb  = bid & 31;
    const int b   = (bid >> 5) & 7;
    const int dir = (bid >> 8) & 1;

    const v8h* __restrict__ qf = form + (size_t)dir * NPC + (size_t)b * NPTS;
    const v8h* __restrict__ tf = form + (size_t)(1 - dir) * NPC + (size_t)b * NPTS;

    const int tid  = threadIdx.x;
    const int lane = tid & 63;
    const int w    = tid >> 6;
    const int c31  = lane & 31;
    const int rowbase = rb * 256;

    v8h a0 = {}, a1 = {};
    if (lane < 32) {
        const _Float16 m2 = (_Float16)(-2.0f);
        v8h f = qf[rowbase + w * 64 + lane];
        a0[0] = m2 * f[0]; a0[1] = m2 * f[1]; a0[2] = m2 * f[2];
        a0[3] = (_Float16)1.0f; a0[4] = f[3];
        f = qf[rowbase + w * 64 + 32 + lane];
        a1[0] = m2 * f[0]; a1[1] = m2 * f[1]; a1[2] = m2 * f[2];
        a1[3] = (_Float16)1.0f; a1[4] = f[3];
    }

    unsigned rm0[16], rm1[16];
#pragma unroll
    for (int r = 0; r < 16; ++r) { rm0[r] = 0x7F7F7F7FU; rm1[r] = 0x7F7F7F7FU; }

    __shared__ v8h bsh[CHUNK];
    const v16f vzero = {};

    for (int ch = 0; ch < COLS / CHUNK; ++ch) {
        __syncthreads();
        const v8h* __restrict__ g = tf + ch * CHUNK;
#pragma unroll
        for (int k = 0; k < CHUNK / BLOCK; ++k)
            bsh[k * BLOCK + tid] = g[k * BLOCK + tid];
        __syncthreads();

#pragma unroll
        for (int cc = 0; cc < CHUNK / 64; ++cc) {
            const v8h b0 = bsh[cc * 64 + c31];
            const v8h b1 = bsh[cc * 64 + 32 + c31];
            __builtin_amdgcn_s_setprio(1);
            v16f p0 = MFMA(a0, b0);
            v16f q0 = MFMA(a0, b1);
            v16f p1 = MFMA(a1, b0);
            v16f q1 = MFMA(a1, b1);
            __builtin_amdgcn_s_setprio(0);
#pragma unroll
            for (int r = 0; r < 16; ++r)
                rm0[r] = umin2(rm0[r], umin2(__builtin_bit_cast(unsigned, p0[r]),
                                             __builtin_bit_cast(unsigned, q0[r])));
#pragma unroll
            for (int r = 0; r < 16; ++r)
                rm1[r] = umin2(rm1[r], umin2(__builtin_bit_cast(unsigned, p1[r]),
                                             __builtin_bit_cast(unsigned, q1[r])));
        }
    }

    float acc = 0.0f;
#pragma unroll
    for (int s = 0; s < 2; ++s) {
#pragma unroll
        for (int r = 0; r < 16; ++r) {
            unsigned u = s ? rm1[r] : rm0[r];
            u = umin2(u, __shfl_xor(u, 1));
            u = umin2(u, __shfl_xor(u, 2));
            u = umin2(u, __shfl_xor(u, 4));
            u = umin2(u, __shfl_xor(u, 8));
            u = umin2(u, __shfl_xor(u, 16));
            if ((lane & 31) == 0) {
                float v = __builtin_bit_cast(float, u);
                acc += sqrtf(fmaxf(fmaxf(v, 0.0f), EPSV));
            }
        }
    }
    acc += __shfl_xor(acc, 32);

    __syncthreads();
    float* red = (float*)bsh;
    if (lane == 0) red[w] = acc;
    __syncthreads();
    if (tid == 0) {
        float s = red[0] + red[1] + red[2] + red[3];
        unsigned long long fx = (unsigned long long)((double)s * FXSCALE + 0.5);
        atomicAdd(counter, fx);
    }
}

extern "C" void kernel_launch(void* const* d_in, const int* in_sizes, int n_in,
                              void* d_out, int out_size, void* d_ws, size_t ws_size,
                              hipStream_t stream) {
    const float* xyz1 = (const float*)d_in[0];
    const float* xyz2 = (const float*)d_in[1];
    float* out = (float*)d_out;

    const size_t gridNeed = (size_t)NG * CELLS * 4 * 2   // A + B
                          + (size_t)TOTALQ * 16          // C
                          + 16;                          // counter
    if (ws_size >= gridNeed) {
        unsigned* A = (unsigned*)d_ws;
        unsigned* B = A + (size_t)NG * CELLS;
        float4*   C = (float4*)(B + (size_t)NG * CELLS);
        unsigned long long* counter = (unsigned long long*)(C + TOTALQ);

        hipMemsetAsync(A, 0, (size_t)NG * CELLS * 4, stream);
        ggrid_count<<<TOTALQ / 256, 256, 0, stream>>>(xyz1, xyz2, A, counter);
        ggrid_scan<<<NG, 1024, 0, stream>>>(A, B);
        ggrid_scatter<<<TOTALQ / 256, 256, 0, stream>>>(xyz1, xyz2, A, C);
        ggrid_query<<<TOTALQ / 256, 256, 0, stream>>>(C, B, counter);
        chamfer_finalize<<<1, 1, 0, stream>>>(counter, out);
    } else {
        v8h* formbuf = (v8h*)d_ws;                       // 2 MB
        unsigned long long* counter = (unsigned long long*)(formbuf + TOTALQ);

        chamfer_prep<<<TOTALQ / 256, 256, 0, stream>>>(xyz1, xyz2, formbuf, counter);
        chamfer_mfma_min<<<2 * NB * 32, BLOCK, 0, stream>>>(formbuf, counter);
        chamfer_finalize<<<1, 1, 0, stream>>>(counter, out);
    }
}

// Round 23
// 278.594 us; speedup vs baseline: 7.6030x; 7.6030x over previous
//
#include <hip/hip_runtime.h>
#include <math.h>

// Chamfer distance, B=8, N=8192, fp32 in, fp32 scalar out.
//
// R23 — EXACT GRID NN, tail fixed.  R22's query was 2.1ms because clamped
// outlier queries (coords beyond +-4.2) made the stop-margin negative ->
// never terminated -> full-grid serial scan.  Fix: directions where the
// scanned box is clamped to the grid edge are FULLY scanned -> margin +inf
// there (also guarantees termination at ring G-1).  Plus row-run collapse:
// cells at fixed (zz,yy) are ci-contiguous, so a full x-run is one
// [B[first], end(last)) scan -> ~3x fewer dependent B-loads, no md branch.
//
// Exact f32 min distances (absmax 0.0 vs np confirmed in R22); merge via
// u64 fixed-point atomicAdd (order-independent => deterministic).
// Fallback: if ws_size < ~6.3MB, the proven R15 MFMA path (45.5 us).

#define NPTS   8192
#define NB     8
#define NPC    (NB * NPTS)         // 65536
#define TOTALQ (2 * NPC)           // 131072
#define EPSV   1e-12f
#define FXSCALE 67108864.0         // 2^26

// ---- grid params ----
#define G      32
#define CELLS  (G * G * G)         // 32768
#define NG     16                  // (side,b) grids
#define XMIN   (-4.2f)
#define RANGE  (8.4f)
#define INVH   ((float)G / RANGE)
#define H      (RANGE / (float)G)

__device__ __forceinline__ int cellof(float v) {
    int c = (int)floorf((v - XMIN) * INVH);
    return c < 0 ? 0 : (c > G - 1 ? G - 1 : c);
}

// K1: count points per cell (A pre-zeroed by memset); zero the counter.
__global__ __launch_bounds__(256) void ggrid_count(
    const float* __restrict__ xyz1, const float* __restrict__ xyz2,
    unsigned* __restrict__ A, unsigned long long* __restrict__ counter)
{
    const int gid = blockIdx.x * 256 + threadIdx.x;      // [0, TOTALQ)
    if (gid == 0) counter[0] = 0ULL;
    const int side  = gid >> 16;
    const int local = gid & (NPC - 1);
    const float* p = (side ? xyz2 : xyz1) + 3 * (size_t)local;
    const int ci = (cellof(p[2]) << 10) | (cellof(p[1]) << 5) | cellof(p[0]);
    const int g  = (side << 3) | (local >> 13);
    atomicAdd(&A[(g << 15) | ci], 1u);
}

// K2: per-grid exclusive scan (16 blocks x 1024 thr, 32 cells/thread).
// Writes offsets to B and initializes A as the scatter cursor.
__global__ __launch_bounds__(1024) void ggrid_scan(
    unsigned* __restrict__ A, unsigned* __restrict__ B)
{
    const int g = blockIdx.x;                  // [0, NG)
    const int t = threadIdx.x;
    const unsigned gbase = (unsigned)g << 15;

    unsigned mysum = 0;
#pragma unroll
    for (int c = 0; c < 32; ++c) mysum += A[gbase + t * 32 + c];

    __shared__ unsigned ls[1024];
    ls[t] = mysum;
    __syncthreads();
    for (int s = 1; s < 1024; s <<= 1) {
        unsigned v = (t >= s) ? ls[t - s] : 0u;
        __syncthreads();
        ls[t] += v;
        __syncthreads();
    }
    unsigned run = (unsigned)g * NPTS + (ls[t] - mysum);
#pragma unroll
    for (int c = 0; c < 32; ++c) {
        const unsigned idx = gbase + t * 32 + c;
        const unsigned cnt = A[idx];
        B[idx] = run;
        A[idx] = run;          // cursor for scatter
        run += cnt;
    }
}

// K3: scatter points into sorted order C[pos] = (x,y,z,0).
__global__ __launch_bounds__(256) void ggrid_scatter(
    const float* __restrict__ xyz1, const float* __restrict__ xyz2,
    unsigned* __restrict__ A, float4* __restrict__ C)
{
    const int gid = blockIdx.x * 256 + threadIdx.x;
    const int side  = gid >> 16;
    const int local = gid & (NPC - 1);
    const float* p = (side ? xyz2 : xyz1) + 3 * (size_t)local;
    const float x = p[0], y = p[1], z = p[2];
    const int ci = (cellof(z) << 10) | (cellof(y) << 5) | cellof(x);
    const int g  = (side << 3) | (local >> 13);
    const unsigned pos = atomicAdd(&A[(g << 15) | ci], 1u);
    C[pos] = make_float4(x, y, z, 0.0f);
}

// K4: one lane per query (sorted order), expanding-ring exact NN with
// row-run scans, then sqrt + block sum + one u64 fixed-point atomicAdd.
__global__ __launch_bounds__(256) void ggrid_query(
    const float4* __restrict__ C, const unsigned* __restrict__ B,
    unsigned long long* __restrict__ counter)
{
    const int gi   = blockIdx.x * 256 + threadIdx.x;     // [0, TOTALQ)
    const int tid  = threadIdx.x;
    const int lane = tid & 63;
    const int w    = tid >> 6;

    const int g_q  = gi >> 13;                 // [0,16): side*8+b
    const int side = g_q >> 3;
    const int b    = g_q & 7;
    const int g_t  = ((1 - side) << 3) | b;
    const unsigned ct   = (unsigned)g_t << 15; // target cell base in B
    const unsigned tend = (unsigned)(g_t + 1) * NPTS;

    const float4 q = C[gi];
    const int cx = cellof(q.x), cy = cellof(q.y), cz = cellof(q.z);

    float best = 3.4e38f;

    // Scan all points of cells (xa..xb, yy, zz): ci-contiguous -> one range.
#define SCAN_RUN(xa, xb, yy, zz)                                             \
    {                                                                        \
        const unsigned cis = (unsigned)(((zz) << 10) | ((yy) << 5) | (xa));  \
        const unsigned cie = (unsigned)(((zz) << 10) | ((yy) << 5) | (xb));  \
        const unsigned s = B[ct | cis];                                      \
        const unsigned e = (cie == CELLS - 1) ? tend : B[ct + cie + 1];      \
        for (unsigned j = s; j < e; ++j) {                                   \
            const float4 p = C[j];                                           \
            const float dx = q.x - p.x;                                      \
            const float dy = q.y - p.y;                                      \
            const float dz = q.z - p.z;                                      \
            best = fminf(best, fmaf(dx, dx, fmaf(dy, dy, dz * dz)));         \
        }                                                                    \
    }

    for (int r = 0; r < G; ++r) {
        if (r == 0) {
            SCAN_RUN(cx, cx, cy, cz);
        } else {
            const int z0 = max(cz - r, 0), z1 = min(cz + r, G - 1);
            const int y0 = max(cy - r, 0), y1 = min(cy + r, G - 1);
            const int x0 = max(cx - r, 0), x1 = min(cx + r, G - 1);
            for (int zz = z0; zz <= z1; ++zz) {
                const int az = abs(zz - cz);
                for (int yy = y0; yy <= y1; ++yy) {
                    const int ay = abs(yy - cy);
                    if (az == r || ay == r) {
                        SCAN_RUN(x0, x1, yy, zz);       // full shell row
                    } else {
                        if (cx - r >= 0)     SCAN_RUN(cx - r, cx - r, yy, zz);
                        if (cx + r <= G - 1) SCAN_RUN(cx + r, cx + r, yy, zz);
                    }
                }
            }
        }
        // Stop bound: distance from q to the scanned-box boundary.
        // Directions clamped to the grid edge are FULLY scanned -> +inf
        // (this also guarantees termination and fixes clamped outliers).
        float m = 3.4e38f;
        if (cx - r > 0)     m = fminf(m, q.x - (XMIN + (cx - r) * H));
        if (cx + r < G - 1) m = fminf(m, (XMIN + (cx + r + 1) * H) - q.x);
        if (cy - r > 0)     m = fminf(m, q.y - (XMIN + (cy - r) * H));
        if (cy + r < G - 1) m = fminf(m, (XMIN + (cy + r + 1) * H) - q.y);
        if (cz - r > 0)     m = fminf(m, q.z - (XMIN + (cz - r) * H));
        if (cz + r < G - 1) m = fminf(m, (XMIN + (cz + r + 1) * H) - q.z);
        if (best <= m * m) break;
    }
#undef SCAN_RUN

    float acc = sqrtf(fmaxf(fmaxf(best, 0.0f), EPSV));
#pragma unroll
    for (int off = 1; off < 64; off <<= 1) acc += __shfl_xor(acc, off);

    __shared__ float red[4];
    __syncthreads();
    if (lane == 0) red[w] = acc;
    __syncthreads();
    if (tid == 0) {
        const float s = red[0] + red[1] + red[2] + red[3];
        atomicAdd(counter, (unsigned long long)((double)s * FXSCALE + 0.5));
    }
}

__global__ void chamfer_finalize(
    const unsigned long long* __restrict__ counter, float* __restrict__ out)
{
    out[0] = (float)((double)counter[0] * (1.0 / FXSCALE) / (double)TOTALQ);
}

// ================= R15 fallback (proven 45.5 us) =================
#define BLOCK  256
#define CHUNK  1024
#define COLS   NPTS

typedef _Float16 v8h  __attribute__((ext_vector_type(8)));
typedef float    v16f __attribute__((ext_vector_type(16)));

__global__ __launch_bounds__(256) void chamfer_prep(
    const float* __restrict__ xyz1, const float* __restrict__ xyz2,
    v8h* __restrict__ form, unsigned long long* __restrict__ counter)
{
    const int gid = blockIdx.x * 256 + threadIdx.x;
    if (gid == 0) counter[0] = 0ULL;
    const float* __restrict__ src = (gid < NPC) ? xyz1 : xyz2;
    const int i = (gid < NPC) ? gid : gid - NPC;
    float x = src[3 * i], y = src[3 * i + 1], z = src[3 * i + 2];
    _Float16 xh = (_Float16)x, yh = (_Float16)y, zh = (_Float16)z;
    float xf = (float)xh, yf = (float)yh, zf = (float)zh;
    float n = fmaf(xf, xf, fmaf(yf, yf, zf * zf));
    v8h bv = {};
    bv[0] = xh; bv[1] = yh; bv[2] = zh;
    bv[3] = (_Float16)n; bv[4] = (_Float16)1.0f;
    form[gid] = bv;
}

#define MFMA(va, vb) __builtin_amdgcn_mfma_f32_32x32x16_f16((va), (vb), vzero, 0, 0, 0)

__device__ __forceinline__ unsigned umin2(unsigned a, unsigned b) {
    return a < b ? a : b;
}

__global__ __launch_bounds__(BLOCK, 4) void chamfer_mfma_min(
    const v8h* __restrict__ form, unsigned long long* __restrict__ counter)
{
    const int bid = blockIdx.x;
    const int rb  = bid & 31;
    const int b   = (bid >> 5) & 7;
    const int dir = (bid >> 8) & 1;

    const v8h* __restrict__ qf = form + (size_t)dir * NPC + (size_t)b * NPTS;
    const v8h* __restrict__ tf = form + (size_t)(1 - dir) * NPC + (size_t)b * NPTS;

    const int tid  = threadIdx.x;
    const int lane = tid & 63;
    const int w    = tid >> 6;
    const int c31  = lane & 31;
    const int rowbase = rb * 256;

    v8h a0 = {}, a1 = {};
    if (lane < 32) {
        const _Float16 m2 = (_Float16)(-2.0f);
        v8h f = qf[rowbase + w * 64 + lane];
        a0[0] = m2 * f[0]; a0[1] = m2 * f[1]; a0[2] = m2 * f[2];
        a0[3] = (_Float16)1.0f; a0[4] = f[3];
        f = qf[rowbase + w * 64 + 32 + lane];
        a1[0] = m2 * f[0]; a1[1] = m2 * f[1]; a1[2] = m2 * f[2];
        a1[3] = (_Float16)1.0f; a1[4] = f[3];
    }

    unsigned rm0[16], rm1[16];
#pragma unroll
    for (int r = 0; r < 16; ++r) { rm0[r] = 0x7F7F7F7FU; rm1[r] = 0x7F7F7F7FU; }

    __shared__ v8h bsh[CHUNK];
    const v16f vzero = {};

    for (int ch = 0; ch < COLS / CHUNK; ++ch) {
        __syncthreads();
        const v8h* __restrict__ g = tf + ch * CHUNK;
#pragma unroll
        for (int k = 0; k < CHUNK / BLOCK; ++k)
            bsh[k * BLOCK + tid] = g[k * BLOCK + tid];
        __syncthreads();

#pragma unroll
        for (int cc = 0; cc < CHUNK / 64; ++cc) {
            const v8h b0 = bsh[cc * 64 + c31];
            const v8h b1 = bsh[cc * 64 + 32 + c31];
            __builtin_amdgcn_s_setprio(1);
            v16f p0 = MFMA(a0, b0);
            v16f q0 = MFMA(a0, b1);
            v16f p1 = MFMA(a1, b0);
            v16f q1 = MFMA(a1, b1);
            __builtin_amdgcn_s_setprio(0);
#pragma unroll
            for (int r = 0; r < 16; ++r)
                rm0[r] = umin2(rm0[r], umin2(__builtin_bit_cast(unsigned, p0[r]),
                                             __builtin_bit_cast(unsigned, q0[r])));
#pragma unroll
            for (int r = 0; r < 16; ++r)
                rm1[r] = umin2(rm1[r], umin2(__builtin_bit_cast(unsigned, p1[r]),
                                             __builtin_bit_cast(unsigned, q1[r])));
        }
    }

    float acc = 0.0f;
#pragma unroll
    for (int s = 0; s < 2; ++s) {
#pragma unroll
        for (int r = 0; r < 16; ++r) {
            unsigned u = s ? rm1[r] : rm0[r];
            u = umin2(u, __shfl_xor(u, 1));
            u = umin2(u, __shfl_xor(u, 2));
            u = umin2(u, __shfl_xor(u, 4));
            u = umin2(u, __shfl_xor(u, 8));
            u = umin2(u, __shfl_xor(u, 16));
            if ((lane & 31) == 0) {
                float v = __builtin_bit_cast(float, u);
                acc += sqrtf(fmaxf(fmaxf(v, 0.0f), EPSV));
            }
        }
    }
    acc += __shfl_xor(acc, 32);

    __syncthreads();
    float* red = (float*)bsh;
    if (lane == 0) red[w] = acc;
    __syncthreads();
    if (tid == 0) {
        float s = red[0] + red[1] + red[2] + red[3];
        unsigned long long fx = (unsigned long long)((double)s * FXSCALE + 0.5);
        atomicAdd(counter, fx);
    }
}

extern "C" void kernel_launch(void* const* d_in, const int* in_sizes, int n_in,
                              void* d_out, int out_size, void* d_ws, size_t ws_size,
                              hipStream_t stream) {
    const float* xyz1 = (const float*)d_in[0];
    const float* xyz2 = (const float*)d_in[1];
    float* out = (float*)d_out;

    const size_t gridNeed = (size_t)NG * CELLS * 4 * 2   // A + B
                          + (size_t)TOTALQ * 16          // C
                          + 16;                          // counter
    if (ws_size >= gridNeed) {
        unsigned* A = (unsigned*)d_ws;
        unsigned* B = A + (size_t)NG * CELLS;
        float4*   C = (float4*)(B + (size_t)NG * CELLS);
        unsigned long long* counter = (unsigned long long*)(C + TOTALQ);

        hipMemsetAsync(A, 0, (size_t)NG * CELLS * 4, stream);
        ggrid_count<<<TOTALQ / 256, 256, 0, stream>>>(xyz1, xyz2, A, counter);
        ggrid_scan<<<NG, 1024, 0, stream>>>(A, B);
        ggrid_scatter<<<TOTALQ / 256, 256, 0, stream>>>(xyz1, xyz2, A, C);
        ggrid_query<<<TOTALQ / 256, 256, 0, stream>>>(C, B, counter);
        chamfer_finalize<<<1, 1, 0, stream>>>(counter, out);
    } else {
        v8h* formbuf = (v8h*)d_ws;                       // 2 MB
        unsigned long long* counter = (unsigned long long*)(formbuf + TOTALQ);

        chamfer_prep<<<TOTALQ / 256, 256, 0, stream>>>(xyz1, xyz2, formbuf, counter);
        chamfer_mfma_min<<<2 * NB * 32, BLOCK, 0, stream>>>(formbuf, counter);
        chamfer_finalize<<<1, 1, 0, stream>>>(counter, out);
    }
}

// Round 24
// 45.649 us; speedup vs baseline: 46.4007x; 6.1029x over previous
//
#include <hip/hip_runtime.h>
#include <math.h>

// Chamfer distance via MFMA, B=8, N=8192, fp32 in, fp32 scalar out.
// FINAL — R15 structure (best of 24 rounds: 45.5 us total, verified twice).
//
// d(q,t) = |q|^2 + |t|^2 - 2 q.t  ==  dot(A_row(q), B_col(t)) with K=5:
//   A_row = (-2x_q, -2y_q, -2z_q, 1, |q|^2),  B_col = (x_t, y_t, z_t, |t|^2, 1)
// in f16 (zero-padded to K=16).  One v_mfma_f32_32x32x16_f16 -> a 32x32 tile
// of complete squared distances in fp32.
//
// Why this is the plateau (session evidence):
//  - main kernel ~40 us = LDS-read ~10 + MFMA ~13 + fold-VALU ~14 serial sum;
//    10 scheduling/structure variants (SWP, sched_barrier, asm min3,
//    occupancy 2->6 w/SIMD, barrier-free, DMA dbuf, global-direct) all
//    nulled, raced the MFMA writeback, or spilled (FETCH>>5MB canary).
//  - transpose-symmetry (halve tiles) costs more col-extraction VALU+DS
//    than it saves (R18/R19: 66us).
//  - exact spatial-grid NN (R22/R23): absmax 0.0 but latency-bound query
//    (2 waves/SIMD by query count) + ~43us fixed pipeline overhead ->
//    floor ~= this kernel's measured total; abandoned on arithmetic.
//
// prep:   clouds -> packed f16 form (x,y,z,n,1,0,0,0); zero sum counter.
// main:   512 blocks = dir(2) x batch(8) x rowblock(32); 4 waves x 2 strips
//         = 256 rows/block, all 8192 cols -> rowmins block-final; epilogue
//         does sqrt + block-sum + ONE u64 fixed-point atomicAdd per block
//         (order-independent => deterministic).  u32 min fold (squared
//         dists are uint-monotone).
// final:  1 thread: out = counter / 2^26 / TOTALQ.

#define NPTS   8192
#define NB     8
#define NPC    (NB * NPTS)         // 65536
#define BLOCK  256
#define CHUNK  1024
#define COLS   NPTS                // all cols per block
#define TOTALQ (2 * NPC)           // 131072
#define EPSV   1e-12f
#define FXSCALE 67108864.0         // 2^26

typedef _Float16 v8h  __attribute__((ext_vector_type(8)));
typedef float    v16f __attribute__((ext_vector_type(16)));

__global__ __launch_bounds__(256) void chamfer_prep(
    const float* __restrict__ xyz1, const float* __restrict__ xyz2,
    v8h* __restrict__ form, unsigned long long* __restrict__ counter)
{
    const int gid = blockIdx.x * 256 + threadIdx.x;      // [0, TOTALQ)
    if (gid == 0) counter[0] = 0ULL;
    const float* __restrict__ src = (gid < NPC) ? xyz1 : xyz2;
    const int i = (gid < NPC) ? gid : gid - NPC;
    float x = src[3 * i], y = src[3 * i + 1], z = src[3 * i + 2];
    _Float16 xh = (_Float16)x, yh = (_Float16)y, zh = (_Float16)z;
    float xf = (float)xh, yf = (float)yh, zf = (float)zh;
    float n = fmaf(xf, xf, fmaf(yf, yf, zf * zf));
    v8h bv = {};
    bv[0] = xh; bv[1] = yh; bv[2] = zh;
    bv[3] = (_Float16)n; bv[4] = (_Float16)1.0f;
    form[gid] = bv;
}

#define MFMA(va, vb) __builtin_amdgcn_mfma_f32_32x32x16_f16((va), (vb), vzero, 0, 0, 0)

__device__ __forceinline__ unsigned umin2(unsigned a, unsigned b) {
    return a < b ? a : b;
}

__global__ __launch_bounds__(BLOCK, 4) void chamfer_mfma_min(
    const v8h* __restrict__ form, unsigned long long* __restrict__ counter)
{
    const int bid = blockIdx.x;             // [0, 512)
    const int rb  = bid & 31;
    const int b   = (bid >> 5) & 7;
    const int dir = (bid >> 8) & 1;

    const v8h* __restrict__ qf = form + (size_t)dir * NPC + (size_t)b * NPTS;
    const v8h* __restrict__ tf = form + (size_t)(1 - dir) * NPC + (size_t)b * NPTS;

    const int tid  = threadIdx.x;
    const int lane = tid & 63;
    const int w    = tid >> 6;              // wave 0..3, two 32-row strips each
    const int c31  = lane & 31;
    const int rowbase = rb * 256;

    // A fragments: lanes<32 carry k=0..7 (5 live slots); lanes>=32 carry
    // k=8..15 which are all zero.
    v8h a0 = {}, a1 = {};
    if (lane < 32) {
        const _Float16 m2 = (_Float16)(-2.0f);
        v8h f = qf[rowbase + w * 64 + lane];
        a0[0] = m2 * f[0]; a0[1] = m2 * f[1]; a0[2] = m2 * f[2];
        a0[3] = (_Float16)1.0f; a0[4] = f[3];
        f = qf[rowbase + w * 64 + 32 + lane];
        a1[0] = m2 * f[0]; a1[1] = m2 * f[1]; a1[2] = m2 * f[2];
        a1[3] = (_Float16)1.0f; a1[4] = f[3];
    }

    unsigned rm0[16], rm1[16];
#pragma unroll
    for (int r = 0; r < 16; ++r) { rm0[r] = 0x7F7F7F7FU; rm1[r] = 0x7F7F7F7FU; }

    __shared__ v8h bsh[CHUNK];              // 16 KB
    const v16f vzero = {};

    for (int ch = 0; ch < COLS / CHUNK; ++ch) {
        __syncthreads();
        const v8h* __restrict__ g = tf + ch * CHUNK;
#pragma unroll
        for (int k = 0; k < CHUNK / BLOCK; ++k)
            bsh[k * BLOCK + tid] = g[k * BLOCK + tid];   // b128 in, b128 out
        __syncthreads();

#pragma unroll
        for (int cc = 0; cc < CHUNK / 64; ++cc) {
            const v8h b0 = bsh[cc * 64 + c31];           // broadcast b128
            const v8h b1 = bsh[cc * 64 + 32 + c31];
            __builtin_amdgcn_s_setprio(1);
            v16f p0 = MFMA(a0, b0);
            v16f q0 = MFMA(a0, b1);
            v16f p1 = MFMA(a1, b0);
            v16f q1 = MFMA(a1, b1);
            __builtin_amdgcn_s_setprio(0);
#pragma unroll
            for (int r = 0; r < 16; ++r)
                rm0[r] = umin2(rm0[r], umin2(__builtin_bit_cast(unsigned, p0[r]),
                                             __builtin_bit_cast(unsigned, q0[r])));
#pragma unroll
            for (int r = 0; r < 16; ++r)
                rm1[r] = umin2(rm1[r], umin2(__builtin_bit_cast(unsigned, p1[r]),
                                             __builtin_bit_cast(unsigned, q1[r])));
        }
    }

    // Epilogue: butterfly row-min across the 32 lanes sharing each row
    // (rowmins are FINAL: this block saw all 8192 cols), sqrt, block-sum,
    // one u64 fixed-point atomicAdd (order-independent => deterministic).
    float acc = 0.0f;
#pragma unroll
    for (int s = 0; s < 2; ++s) {
#pragma unroll
        for (int r = 0; r < 16; ++r) {
            unsigned u = s ? rm1[r] : rm0[r];
            u = umin2(u, __shfl_xor(u, 1));
            u = umin2(u, __shfl_xor(u, 2));
            u = umin2(u, __shfl_xor(u, 4));
            u = umin2(u, __shfl_xor(u, 8));
            u = umin2(u, __shfl_xor(u, 16));
            if ((lane & 31) == 0) {
                float v = __builtin_bit_cast(float, u);
                acc += sqrtf(fmaxf(fmaxf(v, 0.0f), EPSV));
            }
        }
    }
    acc += __shfl_xor(acc, 32);             // lane 0: this wave's 64 rows

    __syncthreads();                        // safe to reuse bsh
    float* red = (float*)bsh;
    if (lane == 0) red[w] = acc;
    __syncthreads();
    if (tid == 0) {
        float s = red[0] + red[1] + red[2] + red[3];
        unsigned long long fx = (unsigned long long)((double)s * FXSCALE + 0.5);
        atomicAdd(counter, fx);
    }
}

__global__ void chamfer_finalize(
    const unsigned long long* __restrict__ counter, float* __restrict__ out)
{
    out[0] = (float)((double)counter[0] * (1.0 / FXSCALE) / (double)TOTALQ);
}

extern "C" void kernel_launch(void* const* d_in, const int* in_sizes, int n_in,
                              void* d_out, int out_size, void* d_ws, size_t ws_size,
                              hipStream_t stream) {
    const float* xyz1 = (const float*)d_in[0];
    const float* xyz2 = (const float*)d_in[1];
    float* out = (float*)d_out;

    v8h* formbuf = (v8h*)d_ws;                                   // TOTALQ v8h = 2 MB
    unsigned long long* counter = (unsigned long long*)(formbuf + TOTALQ);

    chamfer_prep<<<TOTALQ / 256, 256, 0, stream>>>(xyz1, xyz2, formbuf, counter);
    chamfer_mfma_min<<<2 * NB * 32, BLOCK, 0, stream>>>(formbuf, counter);
    chamfer_finalize<<<1, 1, 0, stream>>>(counter, out);
}